// Round 5
// baseline (43.619 us; speedup 1.0000x reference)
//
#include <hip/hip_runtime.h>

#define GG   48
#define DD   256
#define HH   30
#define PP   1128          // GG*(GG-1)/2
#define VROW 264           // fp16 elems per padded LDS row (528 B, 16B-aligned)

#define OFF(i) (((i) * (95 - (i))) >> 1)   // pairs before row i (G=48)

typedef _Float16 half8 __attribute__((ext_vector_type(8)));
typedef _Float16 half4 __attribute__((ext_vector_type(4)));
typedef float    f32x4 __attribute__((ext_vector_type(4)));

__device__ __forceinline__ float sg(float x) { return 1.0f / (1.0f + __expf(-x)); }

__global__ __launch_bounds__(512, 4)
void afm_kernel(const int* __restrict__ group, const float* __restrict__ pe,
                const float* __restrict__ fe, const float* __restrict__ p,
                const float* __restrict__ W1, const float* __restrict__ b1,
                const float* __restrict__ W2, const float* __restrict__ b2,
                float* __restrict__ out)
{
    __shared__ __align__(16) _Float16 v[GG][VROW];      // 25344 B
    __shared__ __align__(16) union SU {
        _Float16 w1t[32][VROW];                          // 16896 B (rows: 30 W1 cols, p, 0)
        struct { float a_s[PP]; float s_s[PP]; } r;      // 9024 B, live after w1t dies
    } u;
    __shared__ int   gidx[GG];
    __shared__ float b1_s[32];
    __shared__ float w2_s[32];
    __shared__ float red[32];

    const int tid  = threadIdx.x;
    const int b    = blockIdx.x;
    const int lane = tid & 63;
    const int wv   = tid >> 6;       // wave 0..7
    const int colB = lane & 15;      // fragment row/col index
    const int kgrp = lane >> 4;      // k-group 0..3

    if (tid < GG) gidx[tid] = group[b * GG + tid];
    if (tid >= 64 && tid < 96) {     // b1/W2 padded to 32 (h=30: p-col, w2=0; h=31: zero)
        int h = tid - 64;
        b1_s[h] = (h < HH) ? b1[h] : 0.0f;
        w2_s[h] = (h < HH) ? W2[h] : 0.0f;
    }
    __syncthreads();

    float ff = (tid < GG) ? fe[gidx[tid]] : 0.0f;

    // stage v rows as fp16 (coalesced float4 gather, 8 rows per sweep)
    {
        int rr = tid >> 6, c = (tid & 63) * 4;
        for (int g0 = 0; g0 < GG; g0 += 8) {
            int g = g0 + rr;
            float4 f = *(const float4*)(pe + (size_t)gidx[g] * DD + c);
            half4 h4 = { (_Float16)f.x, (_Float16)f.y, (_Float16)f.z, (_Float16)f.w };
            *(half4*)&v[g][c] = h4;
        }
    }
    // stage W1^T (fp16), augmented: row 30 = p, row 31 = 0. Flat coalesced read.
    for (int k = tid; k < DD * HH; k += 512) {
        int d = k / HH, h = k - d * HH;
        u.w1t[h][d] = (_Float16)W1[k];
    }
    if (tid < DD) {
        u.w1t[30][tid] = (_Float16)p[tid];
        u.w1t[31][tid] = (_Float16)0.0f;
    }
    __syncthreads();

    // W fragments (A operand): lane holds rows h=colB and h=16+colB, k-chunk kgrp*8
    half8 wf0[8], wf1[8];
    {
        const _Float16* w0p = &u.w1t[colB][kgrp * 8];
        const _Float16* w1p = &u.w1t[16 + colB][kgrp * 8];
#pragma unroll
        for (int kt = 0; kt < 8; ++kt) {
            wf0[kt] = *(const half8*)(w0p + kt * 32);
            wf1[kt] = *(const half8*)(w1p + kt * 32);
        }
    }
    __syncthreads();   // all waves done reading w1t; a_s/s_s may now overwrite it

    const float b2v = b2[0];

    // main loop: tiles (I-block of 16 i's) x (single j), j > I0, wave-strided by 8
    for (int ib = 0; ib < 3; ++ib) {
        const int I0   = ib * 16;
        const int i_me = I0 + colB;          // this lane's pair-i (B-operand col)
        half8 vif[8];
        {
            const _Float16* vr = &v[i_me][kgrp * 8];
#pragma unroll
            for (int kt = 0; kt < 8; ++kt) vif[kt] = *(const half8*)(vr + kt * 32);
        }

        for (int j = I0 + 1 + wv; j < GG; j += 8) {
            const _Float16* vjp = &v[j][kgrp * 8];   // broadcast-class reads
            f32x4 acc0 = {0.f, 0.f, 0.f, 0.f};
            f32x4 acc1 = {0.f, 0.f, 0.f, 0.f};
#pragma unroll
            for (int kt = 0; kt < 8; ++kt) {
                half8 e = vif[kt] * (*(const half8*)(vjp + kt * 32));  // 4 v_pk_mul_f16
                acc0 = __builtin_amdgcn_mfma_f32_16x16x32_f16(wf0[kt], e, acc0, 0, 0, 0);
                acc1 = __builtin_amdgcn_mfma_f32_16x16x32_f16(wf1[kt], e, acc1, 0, 0, 0);
            }
            // C: row = h (kgrp*4+r / +16), col = pair q = colB. In-lane MLP partial:
            float t = 0.0f;
#pragma unroll
            for (int r = 0; r < 4; ++r) {
                int h0 = kgrp * 4 + r;
                t += sg(acc0[r] + b1_s[h0]) * w2_s[h0];
                t += sg(acc1[r] + b1_s[16 + h0]) * w2_s[16 + h0];   // masked terms add 0
            }
            t += __shfl_xor(t, 16);
            t += __shfl_xor(t, 32);
            if (i_me < j) {
                int pidx = OFF(i_me) + (j - i_me - 1);
                if (kgrp == 0) u.r.a_s[pidx] = sg(t + b2v);
                if (kgrp == 3) u.r.s_s[pidx] = acc1[2];   // h = 16+3*4+2 = 30 (e.p)
            }
        }
    }
    __syncthreads();

    // softmax over 1128 pairs + weighted sum + first-order (8-wave reduction)
    float lm = -1e30f;
    for (int q = tid; q < PP; q += 512) lm = fmaxf(lm, u.r.a_s[q]);
#pragma unroll
    for (int o = 32; o > 0; o >>= 1) lm = fmaxf(lm, __shfl_down(lm, o));
    if (lane == 0) red[wv] = lm;
    __syncthreads();
    float m = red[0];
#pragma unroll
    for (int k = 1; k < 8; ++k) m = fmaxf(m, red[k]);

    float ls = 0.0f, ln = 0.0f;
    for (int q = tid; q < PP; q += 512) {
        float ea = __expf(u.r.a_s[q] - m);
        ls += ea;
        ln += ea * u.r.s_s[q];
    }
    float lf = ff;
#pragma unroll
    for (int o = 32; o > 0; o >>= 1) {
        ls += __shfl_down(ls, o);
        ln += __shfl_down(ln, o);
        lf += __shfl_down(lf, o);
    }
    if (lane == 0) {
        red[8 + wv]  = ls;
        red[16 + wv] = ln;
        red[24 + wv] = lf;
    }
    __syncthreads();
    if (tid == 0) {
        float denom = 0.f, num = 0.f, first = 0.f;
#pragma unroll
        for (int k = 0; k < 8; ++k) {
            denom += red[8 + k];
            num   += red[16 + k];
            first += red[24 + k];
        }
        float second = num / denom;
        out[b] = sg(first + second) * 2.0f - 1.0f;
    }
}

extern "C" void kernel_launch(void* const* d_in, const int* in_sizes, int n_in,
                              void* d_out, int out_size, void* d_ws, size_t ws_size,
                              hipStream_t stream)
{
    const int*   group = (const int*)d_in[0];
    const float* pe    = (const float*)d_in[1];
    const float* fe    = (const float*)d_in[2];
    const float* p     = (const float*)d_in[3];
    const float* W1    = (const float*)d_in[4];
    const float* b1    = (const float*)d_in[5];
    const float* W2    = (const float*)d_in[6];
    const float* b2    = (const float*)d_in[7];
    float* out = (float*)d_out;

    afm_kernel<<<512, 512, 0, stream>>>(group, pe, fe, p, W1, b1, W2, b2, out);
}